// Round 4
// baseline (266.905 us; speedup 1.0000x reference)
//
#include <hip/hip_runtime.h>
#include <math.h>

#define DIM    96
#define HEADS  3
#define NTOK   49
#define NWIN   64
#define SCALE  0.17677669529663687f

// ---- workspace layout (bytes) ----
// MODE 2: qkv_wb bf16 @0 (55296) | proj_wb bf16 @55296 (18432) | tabT [64][3][49k][49q] f32 @73728
// MODE 1: qkv_wb bf16 @0         | proj_wb bf16 @55296         | biasT [3][49k][49q] f32 @73728
// MODE 0: biasT [3][49k][49q] f32 @0 (28812)
#define PROJWB_OFFB 55296
#define TAB_OFFB    73728
#define FUSED_TAB_ELEMS (NWIN * HEADS * NTOK * NTOK)
#define BIAS_TAB_ELEMS  (HEADS * NTOK * NTOK)
#define WS_MODE2_NEED (TAB_OFFB + FUSED_TAB_ELEMS * 4)
#define WS_MODE1_NEED (TAB_OFFB + BIAS_TAB_ELEMS * 4)

// ---- LDS layout (unsigned short indices), XOR-swizzled ----
// K   [3][64][32] @ 0      (6144 shorts)  token-major per head
// VT  [3][32][64] @ 6144   (6144 shorts)  d-major (tokens inner)
// total: 12288 shorts = 24576 B
#define K_OFF   0
#define VT_OFF  6144
#define LDS_SHORTS 12288

typedef float  f32x4   __attribute__((ext_vector_type(4)));
typedef __bf16 bf16x8  __attribute__((ext_vector_type(8)));
typedef short  short8  __attribute__((ext_vector_type(8)));
typedef __bf16 bf16x4  __attribute__((ext_vector_type(4)));
typedef short  short4v __attribute__((ext_vector_type(4)));

union U8 { short8  s; bf16x8 b; };
union U4 { short4v s; bf16x4 b; };

// XOR-swizzle on short index: XOR 8-short-granule bits [2:0] of (s>>3) with its bits [5:3].
__device__ __forceinline__ int swz(int s) { return s ^ ((s >> 3) & 56); }

__device__ __forceinline__ unsigned short f2bf(float f) {
    __bf16 h = (__bf16)f;
    union { __bf16 h; unsigned short u; } v; v.h = h; return v.u;
}

__device__ __forceinline__ void ldcvt_g(const float* __restrict__ p, U8& u) {
    float4 f0 = *(const float4*)p;
    float4 f1 = *(const float4*)(p + 4);
    u.b[0] = (__bf16)f0.x; u.b[1] = (__bf16)f0.y; u.b[2] = (__bf16)f0.z; u.b[3] = (__bf16)f0.w;
    u.b[4] = (__bf16)f1.x; u.b[5] = (__bf16)f1.y; u.b[6] = (__bf16)f1.z; u.b[7] = (__bf16)f1.w;
}

// ---- prepass: bf16 weights + TRANSPOSED (bias+mask | bias) table: tabT[..][k][q] ----
__global__ __launch_bounds__(256)
void prep(const float* __restrict__ rpb, const int* __restrict__ rel,
          const float* __restrict__ mask,
          const float* __restrict__ qkv_w, const float* __restrict__ proj_w,
          unsigned short* __restrict__ qkv_wb, unsigned short* __restrict__ proj_wb,
          float* __restrict__ tab, int mode)
{
    int t = blockIdx.x * 256 + threadIdx.x;
    if (mode >= 1) {
        if (t < 3 * DIM * DIM) qkv_wb[t] = f2bf(qkv_w[t]);
        if (t < DIM * DIM)     proj_wb[t] = f2bf(proj_w[t]);
    }
    if (mode == 2) {
        if (t < FUSED_TAB_ELEMS) {
            int win = t / (HEADS * NTOK * NTOK);
            int rem = t - win * (HEADS * NTOK * NTOK);
            int h   = rem / (NTOK * NTOK);
            int ij  = rem - h * (NTOK * NTOK);
            int k = ij / NTOK, q = ij - k * NTOK;           // tabT[k][q]
            tab[t] = rpb[rel[q * NTOK + k] * HEADS + h] + mask[win * (NTOK * NTOK) + q * NTOK + k];
        }
    } else if (t < BIAS_TAB_ELEMS) {
        int h = t / (NTOK * NTOK), ij = t - h * (NTOK * NTOK);
        int k = ij / NTOK, q = ij - k * NTOK;
        tab[t] = rpb[rel[q * NTOK + k] * HEADS + h];
    }
}

// weight fragment load (x32 A-frag, 16B): bf16 from workspace or f32+convert
template<int MODE>
__device__ __forceinline__ void ldw(const unsigned short* __restrict__ wb,
                                    const float* __restrict__ wf, int idx, U8& u) {
    if constexpr (MODE >= 1) u.s = *(const short8*)(wb + idx);
    else                     ldcvt_g(wf + idx, u);
}

template<int MODE>
__global__ __launch_bounds__(256, 5)
void winattn(const float* __restrict__ x,
             const float* __restrict__ mask,
             const float* __restrict__ qkv_w,
             const float* __restrict__ qkv_b,
             const float* __restrict__ proj_w,
             const float* __restrict__ proj_b,
             const unsigned short* __restrict__ qkv_wb,
             const unsigned short* __restrict__ proj_wb,
             const float* __restrict__ tab,
             float* __restrict__ out)
{
    __shared__ __align__(16) unsigned short sbuf[LDS_SHORTS];

    const int tid  = threadIdx.x;
    const int lane = tid & 63;
    const int wave = __builtin_amdgcn_readfirstlane(tid >> 6);
    const int l15  = lane & 15;
    const int quad = lane >> 4;
    const int bnw  = blockIdx.x;
    const int win  = bnw & (NWIN - 1);
    const int tokg = 16 * wave + l15;              // this lane's q-token / x-row
    const int qcl  = (tokg < NTOK) ? tokg : (NTOK - 1);

    const float* fmh[3];
    #pragma unroll
    for (int h = 0; h < 3; ++h)
        fmh[h] = (MODE == 2) ? (tab + (size_t)(win * HEADS + h) * (NTOK * NTOK))
                             : (tab + h * (NTOK * NTOK));
    const float* mw = mask + (size_t)win * (NTOK * NTOK);

    // ================= Phase 1: QKV^T = qkv_w @ x^T (+b), swapped mfma32 =================
    // Output per tile: lane r holds value for (col = 16t+quad*4+r, tok = tokg').
    U8 af[3];
    {
        const float* xw = x + (size_t)bnw * (NTOK * DIM);
        const bool av = (tokg < NTOK);
        #pragma unroll
        for (int s = 0; s < 3; ++s) {
            if (av) ldcvt_g(xw + tokg * DIM + 32 * s + quad * 8, af[s]);
            else {
                #pragma unroll
                for (int j = 0; j < 8; ++j) af[s].b[j] = (__bf16)0.0f;
            }
        }
    }

    U4 qB[3][2];   // Q B-frags, straight to registers
    #pragma unroll
    for (int t = 0; t < 6; ++t) {
        f32x4 acc = {0.f, 0.f, 0.f, 0.f};
        #pragma unroll
        for (int s = 0; s < 3; ++s) {
            U8 w; ldw<MODE>(qkv_wb, qkv_w, (16 * t + l15) * DIM + 32 * s + quad * 8, w);
            acc = __builtin_amdgcn_mfma_f32_16x16x32_bf16(w.b, af[s].b, acc, 0, 0, 0);
        }
        f32x4 qb = *(const f32x4*)(qkv_b + 16 * t + quad * 4);
        #pragma unroll
        for (int r = 0; r < 4; ++r)
            qB[t >> 1][t & 1].b[r] = (__bf16)((acc[r] + qb[r]) * SCALE);
    }
    // K tiles: packed b64 write, token-major [tok][32]
    #pragma unroll
    for (int t = 0; t < 6; ++t) {
        const int tt = t + 6;
        f32x4 acc = {0.f, 0.f, 0.f, 0.f};
        #pragma unroll
        for (int s = 0; s < 3; ++s) {
            U8 w; ldw<MODE>(qkv_wb, qkv_w, (16 * tt + l15) * DIM + 32 * s + quad * 8, w);
            acc = __builtin_amdgcn_mfma_f32_16x16x32_bf16(w.b, af[s].b, acc, 0, 0, 0);
        }
        f32x4 qb = *(const f32x4*)(qkv_b + 16 * tt + quad * 4);
        const int h = t >> 1, dc = t & 1;
        U4 pk;
        #pragma unroll
        for (int r = 0; r < 4; ++r) pk.b[r] = (__bf16)(acc[r] + qb[r]);
        *(short4v*)(sbuf + swz(K_OFF + h * 2048 + tokg * 32 + dc * 16 + quad * 4)) = pk.s;
    }
    // V tiles: d-major VT[d][tok], scalar b16 writes
    #pragma unroll
    for (int t = 0; t < 6; ++t) {
        const int tt = t + 12;
        f32x4 acc = {0.f, 0.f, 0.f, 0.f};
        #pragma unroll
        for (int s = 0; s < 3; ++s) {
            U8 w; ldw<MODE>(qkv_wb, qkv_w, (16 * tt + l15) * DIM + 32 * s + quad * 8, w);
            acc = __builtin_amdgcn_mfma_f32_16x16x32_bf16(w.b, af[s].b, acc, 0, 0, 0);
        }
        f32x4 qb = *(const f32x4*)(qkv_b + 16 * tt + quad * 4);
        const int h = t >> 1, dc = t & 1;
        #pragma unroll
        for (int r = 0; r < 4; ++r)
            sbuf[swz(VT_OFF + h * 2048 + (dc * 16 + quad * 4 + r) * 64 + tokg)] =
                f2bf(acc[r] + qb[r]);
    }

    __syncthreads();   // the ONLY barrier: K and VT visible

    // ====== Phase 2+3 per head: S^T = mfma16(K,Q); in-lane neg-softmax; O^T = mfma16(VT,P) ======
    U4 oB[3][2];
    #pragma unroll
    for (int h = 0; h < 3; ++h) {
        f32x4 st[4];
        #pragma unroll
        for (int t = 0; t < 4; ++t) {
            U4 k0, k1;
            k0.s = *(const short4v*)(sbuf + swz(K_OFF + h * 2048 + (16 * t + l15) * 32 + quad * 4));
            k1.s = *(const short4v*)(sbuf + swz(K_OFF + h * 2048 + (16 * t + l15) * 32 + 16 + quad * 4));
            f32x4 z = {0.f, 0.f, 0.f, 0.f};
            z = __builtin_amdgcn_mfma_f32_16x16x16bf16_1k(k0.s, qB[h][0].s, z, 0, 0, 0);
            z = __builtin_amdgcn_mfma_f32_16x16x16bf16_1k(k1.s, qB[h][1].s, z, 0, 0, 0);
            st[t] = z;
        }
        // lane holds S^T[k = 16t+quad*4+r][q = tokg]: softmax over k is in-lane + 2 shfl
        const float* fm = fmh[h];
        float sval[4][4];
        float mx = -1e30f;
        #pragma unroll
        for (int t = 0; t < 4; ++t)
            #pragma unroll
            for (int r = 0; r < 4; ++r) {
                const int k = 16 * t + quad * 4 + r;
                float s_ = st[t][r] + fm[k * NTOK + qcl];
                if constexpr (MODE != 2) {
                    const int kcl = (k < NTOK) ? k : (NTOK - 1);
                    s_ += mw[qcl * NTOK + kcl];
                }
                sval[t][r] = s_;
                if (k < NTOK) mx = fmaxf(mx, fabsf(s_));
            }
        mx = fmaxf(mx, __shfl_xor(mx, 16));
        mx = fmaxf(mx, __shfl_xor(mx, 32));
        float sm = 0.f;
        U4 pa[4];
        #pragma unroll
        for (int t = 0; t < 4; ++t)
            #pragma unroll
            for (int r = 0; r < 4; ++r) {
                const int k = 16 * t + quad * 4 + r;
                const float s_ = sval[t][r];
                const float e = (k < NTOK) ? __expf(fabsf(s_) - mx) : 0.f;
                sm += e;
                pa[t].b[r] = (__bf16)((s_ > 0.f) ? e : ((s_ < 0.f) ? -e : 0.f));
            }
        sm += __shfl_xor(sm, 16);
        sm += __shfl_xor(sm, 32);
        const float invl = 1.f / sm;
        // O^T = sum_t mfma16(VT-chunk, P): lane r -> O[q=tokg][d = 16dp+quad*4+r]
        #pragma unroll
        for (int dp = 0; dp < 2; ++dp) {
            f32x4 o = {0.f, 0.f, 0.f, 0.f};
            #pragma unroll
            for (int t = 0; t < 4; ++t) {
                U4 vf;
                vf.s = *(const short4v*)(sbuf + swz(VT_OFF + h * 2048 + (16 * dp + l15) * 64 + 16 * t + quad * 4));
                o = __builtin_amdgcn_mfma_f32_16x16x16bf16_1k(vf.s, pa[t].s, o, 0, 0, 0);
            }
            #pragma unroll
            for (int r = 0; r < 4; ++r)
                oB[h][dp].b[r] = (__bf16)(o[r] * invl);
        }
    }

    // ================= Phase 4: out^T = mfma16(proj_w, O), float4 stores =================
    {
        float* op = out + (size_t)bnw * (NTOK * DIM);
        #pragma unroll
        for (int tc = 0; tc < 6; ++tc) {
            f32x4 acc = {0.f, 0.f, 0.f, 0.f};
            #pragma unroll
            for (int kc = 0; kc < 6; ++kc) {
                U4 w;
                if constexpr (MODE >= 1) {
                    w.s = *(const short4v*)(proj_wb + (16 * tc + l15) * DIM + 16 * kc + quad * 4);
                } else {
                    float4 f = *(const float4*)(proj_w + (16 * tc + l15) * DIM + 16 * kc + quad * 4);
                    w.b[0] = (__bf16)f.x; w.b[1] = (__bf16)f.y;
                    w.b[2] = (__bf16)f.z; w.b[3] = (__bf16)f.w;
                }
                acc = __builtin_amdgcn_mfma_f32_16x16x16bf16_1k(w.s, oB[kc >> 1][kc & 1].s, acc, 0, 0, 0);
            }
            f32x4 pb = *(const f32x4*)(proj_b + 16 * tc + quad * 4);
            if (tokg < NTOK)
                *(f32x4*)(op + tokg * DIM + 16 * tc + quad * 4) = acc + pb;
        }
    }
}

extern "C" void kernel_launch(void* const* d_in, const int* in_sizes, int n_in,
                              void* d_out, int out_size, void* d_ws, size_t ws_size,
                              hipStream_t stream) {
    const float* x      = (const float*)d_in[0];
    const float* mask   = (const float*)d_in[1];
    const float* qkv_w  = (const float*)d_in[2];
    const float* qkv_b  = (const float*)d_in[3];
    const float* proj_w = (const float*)d_in[4];
    const float* proj_b = (const float*)d_in[5];
    const float* rpb    = (const float*)d_in[6];
    const int*   rel    = (const int*)d_in[7];
    float* outp         = (float*)d_out;

    int mode;
    if      (ws_size >= (size_t)WS_MODE2_NEED) mode = 2;
    else if (ws_size >= (size_t)WS_MODE1_NEED) mode = 1;
    else                                        mode = 0;

    unsigned short* qkv_wb  = (unsigned short*)d_ws;
    unsigned short* proj_wb = (unsigned short*)((char*)d_ws + PROJWB_OFFB);
    float* tab = (mode >= 1) ? (float*)((char*)d_ws + TAB_OFFB) : (float*)d_ws;

    const int npre = (mode == 2) ? FUSED_TAB_ELEMS
                   : (mode == 1) ? 3 * DIM * DIM
                                 : BIAS_TAB_ELEMS;
    prep<<<(npre + 255) / 256, 256, 0, stream>>>(rpb, rel, mask, qkv_w, proj_w,
                                                 qkv_wb, proj_wb, tab, mode);

    const int n_windows = in_sizes[0] / (NTOK * DIM);   // 4096
    if (mode == 2)
        winattn<2><<<n_windows, 256, 0, stream>>>(x, mask, qkv_w, qkv_b, proj_w, proj_b,
                                                  qkv_wb, proj_wb, tab, outp);
    else if (mode == 1)
        winattn<1><<<n_windows, 256, 0, stream>>>(x, mask, qkv_w, qkv_b, proj_w, proj_b,
                                                  qkv_wb, proj_wb, tab, outp);
    else
        winattn<0><<<n_windows, 256, 0, stream>>>(x, mask, qkv_w, qkv_b, proj_w, proj_b,
                                                  qkv_wb, proj_wb, tab, outp);
}

// Round 5
// 211.667 us; speedup vs baseline: 1.2610x; 1.2610x over previous
//
#include <hip/hip_runtime.h>
#include <math.h>

#define DIM    96
#define HEADS  3
#define NTOK   49
#define NWIN   64
#define SCALE  0.17677669529663687f
#define MW     2          // windows per block

// ---- workspace layout (bytes) ----
// MODE 2: qkv_wb bf16 @0 (55296) | proj_wb bf16 @55296 (18432) | tabT [64][3][49k][49q] f32 @73728
// MODE 1: qkv_wb bf16 @0         | proj_wb bf16 @55296         | biasT [3][49k][49q] f32 @73728
// MODE 0: biasT [3][49k][49q] f32 @0 (28812)
#define PROJWB_OFFB 55296
#define TAB_OFFB    73728
#define FUSED_TAB_ELEMS (NWIN * HEADS * NTOK * NTOK)
#define BIAS_TAB_ELEMS  (HEADS * NTOK * NTOK)
#define WS_MODE2_NEED (TAB_OFFB + FUSED_TAB_ELEMS * 4)
#define WS_MODE1_NEED (TAB_OFFB + BIAS_TAB_ELEMS * 4)

// ---- LDS (short indices), XOR-swizzled ----
// per window: K [3][64][32] @0 (6144 sh) token-major | VT [3][32][64] @6144 (6144 sh) d-major
// window w at offset w*12288; total 24576 sh = 49152 B -> 3 blocks/CU
#define WSTRIDE 12288
#define K_OFF   0
#define VT_OFF  6144
#define LDS_SHORTS (MW * WSTRIDE)

typedef float  f32x4   __attribute__((ext_vector_type(4)));
typedef __bf16 bf16x8  __attribute__((ext_vector_type(8)));
typedef short  short8  __attribute__((ext_vector_type(8)));
typedef __bf16 bf16x4  __attribute__((ext_vector_type(4)));
typedef short  short4v __attribute__((ext_vector_type(4)));

union U8 { short8  s; bf16x8 b; };
union U4 { short4v s; bf16x4 b; };

// XOR-swizzle on short index: XOR 16B-granule bits [5:3] with 128B-line bits [8:6].
// All region bases are 512-short aligned.
__device__ __forceinline__ int swz(int s) { return s ^ ((s >> 3) & 56); }

__device__ __forceinline__ unsigned short f2bf(float f) {
    __bf16 h = (__bf16)f;
    union { __bf16 h; unsigned short u; } v; v.h = h; return v.u;
}

__device__ __forceinline__ void ldcvt_g(const float* __restrict__ p, U8& u) {
    float4 f0 = *(const float4*)p;
    float4 f1 = *(const float4*)(p + 4);
    u.b[0] = (__bf16)f0.x; u.b[1] = (__bf16)f0.y; u.b[2] = (__bf16)f0.z; u.b[3] = (__bf16)f0.w;
    u.b[4] = (__bf16)f1.x; u.b[5] = (__bf16)f1.y; u.b[6] = (__bf16)f1.z; u.b[7] = (__bf16)f1.w;
}

// ---- prepass: bf16 weights + TRANSPOSED (bias+mask | bias) table tabT[..][k][q] ----
__global__ __launch_bounds__(256)
void prep(const float* __restrict__ rpb, const int* __restrict__ rel,
          const float* __restrict__ mask,
          const float* __restrict__ qkv_w, const float* __restrict__ proj_w,
          unsigned short* __restrict__ qkv_wb, unsigned short* __restrict__ proj_wb,
          float* __restrict__ tab, int mode)
{
    int t = blockIdx.x * 256 + threadIdx.x;
    if (mode >= 1) {
        if (t < 3 * DIM * DIM) qkv_wb[t] = f2bf(qkv_w[t]);
        if (t < DIM * DIM)     proj_wb[t] = f2bf(proj_w[t]);
    }
    if (mode == 2) {
        if (t < FUSED_TAB_ELEMS) {
            int win = t / (HEADS * NTOK * NTOK);
            int rem = t - win * (HEADS * NTOK * NTOK);
            int h   = rem / (NTOK * NTOK);
            int ij  = rem - h * (NTOK * NTOK);
            int k = ij / NTOK, q = ij - k * NTOK;
            tab[t] = rpb[rel[q * NTOK + k] * HEADS + h] + mask[win * (NTOK * NTOK) + q * NTOK + k];
        }
    } else if (t < BIAS_TAB_ELEMS) {
        int h = t / (NTOK * NTOK), ij = t - h * (NTOK * NTOK);
        int k = ij / NTOK, q = ij - k * NTOK;
        tab[t] = rpb[rel[q * NTOK + k] * HEADS + h];
    }
}

// x32 A-frag weight load (16B)
template<int MODE>
__device__ __forceinline__ void ldw(const unsigned short* __restrict__ wb,
                                    const float* __restrict__ wf, int idx, U8& u) {
    if constexpr (MODE >= 1) u.s = *(const short8*)(wb + idx);
    else                     ldcvt_g(wf + idx, u);
}
// x16 frag load (8B)
template<int MODE>
__device__ __forceinline__ void ldw4(const unsigned short* __restrict__ wb,
                                     const float* __restrict__ wf, int idx, U4& u) {
    if constexpr (MODE >= 1) u.s = *(const short4v*)(wb + idx);
    else {
        float4 f = *(const float4*)(wf + idx);
        u.b[0] = (__bf16)f.x; u.b[1] = (__bf16)f.y; u.b[2] = (__bf16)f.z; u.b[3] = (__bf16)f.w;
    }
}

template<int MODE>
__global__ __launch_bounds__(256, 3)
void winattn(const float* __restrict__ x,
             const float* __restrict__ mask,
             const float* __restrict__ qkv_w,
             const float* __restrict__ qkv_b,
             const float* __restrict__ proj_w,
             const float* __restrict__ proj_b,
             const unsigned short* __restrict__ qkv_wb,
             const unsigned short* __restrict__ proj_wb,
             const float* __restrict__ tab,
             float* __restrict__ out, int nwin_tot)
{
    __shared__ __align__(16) unsigned short sbuf[LDS_SHORTS];

    const int tid  = threadIdx.x;
    const int lane = tid & 63;
    const int wave = __builtin_amdgcn_readfirstlane(tid >> 6);
    const int l15  = lane & 15;
    const int quad = lane >> 4;
    const int tokg = 16 * wave + l15;
    const int qcl  = (tokg < NTOK) ? tokg : (NTOK - 1);

    int bw[MW];
    const float* fmh[MW][3];
    const float* mww[MW];
    #pragma unroll
    for (int w = 0; w < MW; ++w) {
        int b = blockIdx.x * MW + w;
        bw[w] = (b < nwin_tot) ? b : (nwin_tot - 1);
        const int win = bw[w] & (NWIN - 1);
        #pragma unroll
        for (int h = 0; h < 3; ++h)
            fmh[w][h] = (MODE == 2) ? (tab + (size_t)(win * HEADS + h) * (NTOK * NTOK))
                                    : (tab + h * (NTOK * NTOK));
        mww[w] = mask + (size_t)win * (NTOK * NTOK);
    }

    // ---- x A-frags for both windows (issued first, batched) ----
    U8 af[MW][3];
    #pragma unroll
    for (int w = 0; w < MW; ++w) {
        const float* xw = x + (size_t)bw[w] * (NTOK * DIM);
        #pragma unroll
        for (int s = 0; s < 3; ++s) {
            if (tokg < NTOK) ldcvt_g(xw + tokg * DIM + 32 * s + quad * 8, af[w][s]);
            else {
                #pragma unroll
                for (int j = 0; j < 8; ++j) af[w][s].b[j] = (__bf16)0.0f;
            }
        }
    }

    // ================= Phase 1: QKV^T tiles, tiles-outer / windows-inner =================
    // depth-2 ping-pong prefetch of weight frags + bias
    U4 qB[MW][3][2];
    U8 wpf[2][3];
    f32x4 qbp[2];
    #pragma unroll
    for (int s = 0; s < 3; ++s) {
        ldw<MODE>(qkv_wb, qkv_w, (l15) * DIM + 32 * s + quad * 8, wpf[0][s]);
        ldw<MODE>(qkv_wb, qkv_w, (16 + l15) * DIM + 32 * s + quad * 8, wpf[1][s]);
    }
    qbp[0] = *(const f32x4*)(qkv_b + quad * 4);
    qbp[1] = *(const f32x4*)(qkv_b + 16 + quad * 4);

    #pragma unroll
    for (int t = 0; t < 18; ++t) {
        f32x4 acc[MW];
        #pragma unroll
        for (int w = 0; w < MW; ++w) {
            f32x4 z = {0.f, 0.f, 0.f, 0.f};
            #pragma unroll
            for (int s = 0; s < 3; ++s)
                z = __builtin_amdgcn_mfma_f32_16x16x32_bf16(wpf[t & 1][s].b, af[w][s].b, z, 0, 0, 0);
            acc[w] = z;
        }
        f32x4 qb = qbp[t & 1];
        if (t + 2 < 18) {
            #pragma unroll
            for (int s = 0; s < 3; ++s)
                ldw<MODE>(qkv_wb, qkv_w, (16 * (t + 2) + l15) * DIM + 32 * s + quad * 8, wpf[t & 1][s]);
            qbp[t & 1] = *(const f32x4*)(qkv_b + 16 * (t + 2) + quad * 4);
        }
        if (t < 6) {               // Q -> registers
            const int h = t >> 1, half = t & 1;
            #pragma unroll
            for (int w = 0; w < MW; ++w)
                #pragma unroll
                for (int r = 0; r < 4; ++r)
                    qB[w][h][half].b[r] = (__bf16)((acc[w][r] + qb[r]) * SCALE);
        } else if (t < 12) {       // K -> LDS token-major, packed b64
            const int tt = t - 6, h = tt >> 1, dc = tt & 1;
            #pragma unroll
            for (int w = 0; w < MW; ++w) {
                U4 pk;
                #pragma unroll
                for (int r = 0; r < 4; ++r) pk.b[r] = (__bf16)(acc[w][r] + qb[r]);
                *(short4v*)(sbuf + swz(w * WSTRIDE + K_OFF + h * 2048 + tokg * 32 + dc * 16 + quad * 4)) = pk.s;
            }
        } else {                   // V -> LDS d-major scatter
            const int tt = t - 12, h = tt >> 1, dc = tt & 1;
            #pragma unroll
            for (int w = 0; w < MW; ++w)
                #pragma unroll
                for (int r = 0; r < 4; ++r)
                    sbuf[swz(w * WSTRIDE + VT_OFF + h * 2048 + (dc * 16 + quad * 4 + r) * 64 + tokg)] =
                        f2bf(acc[w][r] + qb[r]);
        }
    }

    // prefetch tab for iteration 0 (h=0,w=0); hides under the barrier drain
    float tv[2][4][4];
    #pragma unroll
    for (int t = 0; t < 4; ++t)
        #pragma unroll
        for (int r = 0; r < 4; ++r) {
            const int k = 16 * t + quad * 4 + r;
            float v = fmh[0][0][k * NTOK + qcl];
            if constexpr (MODE != 2) {
                const int kcl = (k < NTOK) ? k : (NTOK - 1);
                v += mww[0][qcl * NTOK + kcl];
            }
            tv[0][t][r] = v;
        }

    __syncthreads();   // the ONLY barrier: all windows' K and VT visible

    // ====== Phase 2+3: per (head, window): S^T = mfma16(K,Q); in-lane neg-softmax; O^T ======
    U4 oB[MW][3][2];
    #pragma unroll
    for (int h = 0; h < 3; ++h) {
        #pragma unroll
        for (int w = 0; w < MW; ++w) {
            const int it = h * MW + w;
            const int base = w * WSTRIDE;
            f32x4 st[4];
            #pragma unroll
            for (int t = 0; t < 4; ++t) {
                U4 k0, k1;
                k0.s = *(const short4v*)(sbuf + swz(base + K_OFF + h * 2048 + (16 * t + l15) * 32 + quad * 4));
                k1.s = *(const short4v*)(sbuf + swz(base + K_OFF + h * 2048 + (16 * t + l15) * 32 + 16 + quad * 4));
                f32x4 z = {0.f, 0.f, 0.f, 0.f};
                z = __builtin_amdgcn_mfma_f32_16x16x16bf16_1k(k0.s, qB[w][h][0].s, z, 0, 0, 0);
                z = __builtin_amdgcn_mfma_f32_16x16x16bf16_1k(k1.s, qB[w][h][1].s, z, 0, 0, 0);
                st[t] = z;
            }
            // prefetch next iteration's tab while MFMAs are in flight
            if (it < 3 * MW - 1) {
                const int hn = (it + 1) / MW, wn = (it + 1) % MW;
                #pragma unroll
                for (int t = 0; t < 4; ++t)
                    #pragma unroll
                    for (int r = 0; r < 4; ++r) {
                        const int k = 16 * t + quad * 4 + r;
                        float v = fmh[wn][hn][k * NTOK + qcl];
                        if constexpr (MODE != 2) {
                            const int kcl = (k < NTOK) ? k : (NTOK - 1);
                            v += mww[wn][qcl * NTOK + kcl];
                        }
                        tv[(it + 1) & 1][t][r] = v;
                    }
            }
            // lane holds S^T[k=16t+quad*4+r][q=tokg]: in-lane softmax + 2 shfl
            float sval[4][4];
            float mx = -1e30f;
            #pragma unroll
            for (int t = 0; t < 4; ++t)
                #pragma unroll
                for (int r = 0; r < 4; ++r) {
                    const int k = 16 * t + quad * 4 + r;
                    float s_ = st[t][r] + tv[it & 1][t][r];
                    sval[t][r] = s_;
                    if (k < NTOK) mx = fmaxf(mx, fabsf(s_));
                }
            mx = fmaxf(mx, __shfl_xor(mx, 16));
            mx = fmaxf(mx, __shfl_xor(mx, 32));
            float sm = 0.f;
            U4 pa[4];
            #pragma unroll
            for (int t = 0; t < 4; ++t)
                #pragma unroll
                for (int r = 0; r < 4; ++r) {
                    const int k = 16 * t + quad * 4 + r;
                    const float s_ = sval[t][r];
                    const float e = (k < NTOK) ? __expf(fabsf(s_) - mx) : 0.f;
                    sm += e;
                    pa[t].b[r] = (__bf16)((s_ > 0.f) ? e : ((s_ < 0.f) ? -e : 0.f));
                }
            sm += __shfl_xor(sm, 16);
            sm += __shfl_xor(sm, 32);
            const float invl = 1.f / sm;
            #pragma unroll
            for (int dp = 0; dp < 2; ++dp) {
                f32x4 o = {0.f, 0.f, 0.f, 0.f};
                #pragma unroll
                for (int t = 0; t < 4; ++t) {
                    U4 vf;
                    vf.s = *(const short4v*)(sbuf + swz(base + VT_OFF + h * 2048 + (16 * dp + l15) * 64 + 16 * t + quad * 4));
                    o = __builtin_amdgcn_mfma_f32_16x16x16bf16_1k(vf.s, pa[t].s, o, 0, 0, 0);
                }
                #pragma unroll
                for (int r = 0; r < 4; ++r)
                    oB[w][h][dp].b[r] = (__bf16)(o[r] * invl);
            }
        }
    }

    // ================= Phase 4: out^T = mfma16(proj_w, O), batched+pingpong weights =================
    {
        U4 w4pf[2][6];
        f32x4 pbp[2];
        #pragma unroll
        for (int kc = 0; kc < 6; ++kc)
            ldw4<MODE>(proj_wb, proj_w, l15 * DIM + 16 * kc + quad * 4, w4pf[0][kc]);
        pbp[0] = *(const f32x4*)(proj_b + quad * 4);

        #pragma unroll
        for (int tc = 0; tc < 6; ++tc) {
            if (tc + 1 < 6) {
                #pragma unroll
                for (int kc = 0; kc < 6; ++kc)
                    ldw4<MODE>(proj_wb, proj_w, (16 * (tc + 1) + l15) * DIM + 16 * kc + quad * 4,
                               w4pf[(tc + 1) & 1][kc]);
                pbp[(tc + 1) & 1] = *(const f32x4*)(proj_b + 16 * (tc + 1) + quad * 4);
            }
            f32x4 acc[MW];
            #pragma unroll
            for (int w = 0; w < MW; ++w) acc[w] = f32x4{0.f, 0.f, 0.f, 0.f};
            #pragma unroll
            for (int kc = 0; kc < 6; ++kc)
                #pragma unroll
                for (int w = 0; w < MW; ++w)
                    acc[w] = __builtin_amdgcn_mfma_f32_16x16x16bf16_1k(
                        w4pf[tc & 1][kc].s, oB[w][kc >> 1][kc & 1].s, acc[w], 0, 0, 0);
            const f32x4 pb = pbp[tc & 1];
            #pragma unroll
            for (int w = 0; w < MW; ++w) {
                if (tokg < NTOK)
                    *(f32x4*)(out + (size_t)bw[w] * (NTOK * DIM) + tokg * DIM + 16 * tc + quad * 4) =
                        acc[w] + pb;
            }
        }
    }
}

extern "C" void kernel_launch(void* const* d_in, const int* in_sizes, int n_in,
                              void* d_out, int out_size, void* d_ws, size_t ws_size,
                              hipStream_t stream) {
    const float* x      = (const float*)d_in[0];
    const float* mask   = (const float*)d_in[1];
    const float* qkv_w  = (const float*)d_in[2];
    const float* qkv_b  = (const float*)d_in[3];
    const float* proj_w = (const float*)d_in[4];
    const float* proj_b = (const float*)d_in[5];
    const float* rpb    = (const float*)d_in[6];
    const int*   rel    = (const int*)d_in[7];
    float* outp         = (float*)d_out;

    int mode;
    if      (ws_size >= (size_t)WS_MODE2_NEED) mode = 2;
    else if (ws_size >= (size_t)WS_MODE1_NEED) mode = 1;
    else                                        mode = 0;

    unsigned short* qkv_wb  = (unsigned short*)d_ws;
    unsigned short* proj_wb = (unsigned short*)((char*)d_ws + PROJWB_OFFB);
    float* tab = (mode >= 1) ? (float*)((char*)d_ws + TAB_OFFB) : (float*)d_ws;

    const int npre = (mode == 2) ? FUSED_TAB_ELEMS
                   : (mode == 1) ? 3 * DIM * DIM
                                 : BIAS_TAB_ELEMS;
    prep<<<(npre + 255) / 256, 256, 0, stream>>>(rpb, rel, mask, qkv_w, proj_w,
                                                 qkv_wb, proj_wb, tab, mode);

    const int n_windows = in_sizes[0] / (NTOK * DIM);   // 4096
    const int nb = (n_windows + MW - 1) / MW;
    if (mode == 2)
        winattn<2><<<nb, 256, 0, stream>>>(x, mask, qkv_w, qkv_b, proj_w, proj_b,
                                           qkv_wb, proj_wb, tab, outp, n_windows);
    else if (mode == 1)
        winattn<1><<<nb, 256, 0, stream>>>(x, mask, qkv_w, qkv_b, proj_w, proj_b,
                                           qkv_wb, proj_wb, tab, outp, n_windows);
    else
        winattn<0><<<nb, 256, 0, stream>>>(x, mask, qkv_w, qkv_b, proj_w, proj_b,
                                           qkv_wb, proj_wb, tab, outp, n_windows);
}